// Round 2
// baseline (986.042 us; speedup 1.0000x reference)
//
#include <hip/hip_runtime.h>

typedef __bf16 bf16_t;
typedef __bf16 bf16x8 __attribute__((ext_vector_type(8)));
typedef float f32x4 __attribute__((ext_vector_type(4)));

#define LN_EPS 1e-3f

__device__ __forceinline__ void gload_lds16(const void* g, void* l) {
    __builtin_amdgcn_global_load_lds(
        (__attribute__((address_space(1))) void*)(g),
        (__attribute__((address_space(3))) void*)(l), 16, 0, 0);
}

// ---------------- weight prep ----------------
// out[(sel*1024 + h*64 + d)*1024 + c] = w_sel[h][c][d]
__global__ void pack_qkv_w(const float* __restrict__ wq, const float* __restrict__ wk,
                           const float* __restrict__ wv, bf16_t* __restrict__ outp)
{
    int idx = blockIdx.x * 256 + threadIdx.x;       // 0 .. 3*1024*1024-1
    int c   = idx & 1023;
    int n   = idx >> 10;
    int sel = n >> 10;
    int hd  = n & 1023;
    const float* src = (sel == 0) ? wq : (sel == 1) ? wk : wv;
    outp[idx] = (bf16_t)src[((hd >> 6) * 1024 + c) * 64 + (hd & 63)];
}

// out[n*K + k] = in[k*N + n]   (K = 1<<lgK, N = 1<<lgN)
__global__ void transpose_w(const float* __restrict__ in, bf16_t* __restrict__ outp,
                            int lgK, int lgN)
{
    long idx = (long)blockIdx.x * 256 + threadIdx.x;
    long k = idx & ((1L << lgK) - 1);
    long n = idx >> lgK;
    outp[idx] = (bf16_t)in[n + (k << lgN)];
}

// ---------------- layernorm (f32 in -> bf16 LN out) ----------------
__global__ __launch_bounds__(256)
void ln_fwd(const float* __restrict__ in, const float* __restrict__ g,
            const float* __restrict__ be, bf16_t* __restrict__ outp)
{
    const long row = blockIdx.x;
    const int t = threadIdx.x;
    float4 v = ((const float4*)(in + row * 1024))[t];
    float s  = v.x + v.y + v.z + v.w;
    float sq = v.x * v.x + v.y * v.y + v.z * v.z + v.w * v.w;
#pragma unroll
    for (int off = 1; off < 64; off <<= 1) {
        s  += __shfl_xor(s, off);
        sq += __shfl_xor(sq, off);
    }
    __shared__ float red[8];
    if ((t & 63) == 0) { red[(t >> 6) * 2] = s; red[(t >> 6) * 2 + 1] = sq; }
    __syncthreads();
    s  = red[0] + red[2] + red[4] + red[6];
    sq = red[1] + red[3] + red[5] + red[7];
    float mean = s * 0.0009765625f;
    float var  = sq * 0.0009765625f - mean * mean;
    float rstd = rsqrtf(var + LN_EPS);
    float4 gv = ((const float4*)g)[t];
    float4 bv = ((const float4*)be)[t];
    union { bf16_t h[4]; uint2 u; } pk;
    pk.h[0] = (bf16_t)((v.x - mean) * rstd * gv.x + bv.x);
    pk.h[1] = (bf16_t)((v.y - mean) * rstd * gv.y + bv.y);
    pk.h[2] = (bf16_t)((v.z - mean) * rstd * gv.z + bv.z);
    pk.h[3] = (bf16_t)((v.w - mean) * rstd * gv.w + bv.w);
    *(uint2*)(outp + row * 1024 + t * 4) = pk.u;
}

// ---------------- final layernorm (bf16 in + f32 res -> f32 out, res may == out) ----------------
__global__ __launch_bounds__(256)
void ln3_kernel(const bf16_t* __restrict__ in, const float* __restrict__ g,
                const float* __restrict__ be, float* outp, const float* res)
{
    const long row = blockIdx.x;
    const int t = threadIdx.x;
    union { uint2 u; bf16_t h[4]; } pk;
    pk.u = *(const uint2*)(in + row * 1024 + t * 4);
    float v0 = (float)pk.h[0], v1 = (float)pk.h[1], v2 = (float)pk.h[2], v3 = (float)pk.h[3];
    float s  = v0 + v1 + v2 + v3;
    float sq = v0 * v0 + v1 * v1 + v2 * v2 + v3 * v3;
#pragma unroll
    for (int off = 1; off < 64; off <<= 1) {
        s  += __shfl_xor(s, off);
        sq += __shfl_xor(sq, off);
    }
    __shared__ float red[8];
    if ((t & 63) == 0) { red[(t >> 6) * 2] = s; red[(t >> 6) * 2 + 1] = sq; }
    __syncthreads();
    s  = red[0] + red[2] + red[4] + red[6];
    sq = red[1] + red[3] + red[5] + red[7];
    float mean = s * 0.0009765625f;
    float var  = sq * 0.0009765625f - mean * mean;
    float rstd = rsqrtf(var + LN_EPS);
    float4 gv = ((const float4*)g)[t];
    float4 bv = ((const float4*)be)[t];
    float4 rv = ((const float4*)(res + row * 1024))[t];
    float4 ov;
    ov.x = rv.x + (v0 - mean) * rstd * gv.x + bv.x;
    ov.y = rv.y + (v1 - mean) * rstd * gv.y + bv.y;
    ov.z = rv.z + (v2 - mean) * rstd * gv.z + bv.z;
    ov.w = rv.w + (v3 - mean) * rstd * gv.w + bv.w;
    ((float4*)outp)[row * 256 + t] = ov;
}

// ---------------- GEMM: C[M,N] = A[M,K] * Bt[N,K]^T ----------------
// MODE 0: out bf16 = acc
// MODE 1: out f32  = acc + bias[col] + addf32[row,col]
// MODE 2: out bf16 = relu(acc + bias[col])
// MODE 3: out bf16 = acc + bias[col] + (float)addbf16[row,col]   (outp may == addp, elementwise)
template<int MODE>
__global__ __launch_bounds__(256)
void gemm_bt(const bf16_t* __restrict__ A, const bf16_t* __restrict__ Bt,
             void* outp, const float* __restrict__ bias,
             const void* addp, int M, int N, int K)
{
    __shared__ __attribute__((aligned(16))) bf16_t As[128 * 64];
    __shared__ __attribute__((aligned(16))) bf16_t Bs[128 * 64];
    const int tid  = threadIdx.x;
    const int w    = tid >> 6, lane = tid & 63;
    const int l16  = lane & 15, lg = lane >> 4;
    const int wm   = w >> 1, wn = w & 1;
    const long m0  = (long)blockIdx.x * 128;
    const long n0  = (long)blockIdx.y * 128;
    const int srow = lane >> 3;            // 0..7
    const int scol = (lane & 7) * 8;       // element offset in a 64-wide row

    f32x4 acc[4][4] = {};
    const int nkt = K >> 6;
    const bf16_t* Abase = A  + (m0 + 32 * w + srow) * (long)K + scol;
    const bf16_t* Bbase = Bt + (n0 + 32 * w + srow) * (long)K + scol;

    for (int kt = 0; kt < nkt; ++kt) {
        __syncthreads();
#pragma unroll
        for (int i = 0; i < 4; ++i) {
            gload_lds16(Abase + (long)8 * i * K + kt * 64, &As[(32 * w + 8 * i) * 64]);
            gload_lds16(Bbase + (long)8 * i * K + kt * 64, &Bs[(32 * w + 8 * i) * 64]);
        }
        asm volatile("s_waitcnt vmcnt(0)" ::: "memory");
        __syncthreads();
#pragma unroll
        for (int kk = 0; kk < 2; ++kk) {
            bf16x8 a[4], b[4];
#pragma unroll
            for (int f = 0; f < 4; ++f) {
                a[f] = *(const bf16x8*)&As[(wm * 64 + f * 16 + l16) * 64 + kk * 32 + lg * 8];
                b[f] = *(const bf16x8*)&Bs[(wn * 64 + f * 16 + l16) * 64 + kk * 32 + lg * 8];
            }
#pragma unroll
            for (int fm = 0; fm < 4; ++fm)
#pragma unroll
                for (int fn = 0; fn < 4; ++fn)
                    acc[fm][fn] = __builtin_amdgcn_mfma_f32_16x16x32_bf16(
                        a[fm], b[fn], acc[fm][fn], 0, 0, 0);
        }
    }

#pragma unroll
    for (int fm = 0; fm < 4; ++fm) {
#pragma unroll
        for (int fn = 0; fn < 4; ++fn) {
            const long gcol = n0 + wn * 64 + fn * 16 + l16;
            float bv = 0.f;
            if (MODE != 0) bv = bias[gcol];
#pragma unroll
            for (int e = 0; e < 4; ++e) {
                const long grow = m0 + wm * 64 + fm * 16 + lg * 4 + e;
                float v = acc[fm][fn][e];
                if (MODE == 0) {
                    ((bf16_t*)outp)[grow * N + gcol] = (bf16_t)v;
                } else if (MODE == 1) {
                    v += bv + ((const float*)addp)[grow * N + gcol];
                    ((float*)outp)[grow * N + gcol] = v;
                } else if (MODE == 2) {
                    v += bv; v = v > 0.f ? v : 0.f;
                    ((bf16_t*)outp)[grow * N + gcol] = (bf16_t)v;
                } else {
                    v += bv + (float)((const bf16_t*)addp)[grow * N + gcol];
                    ((bf16_t*)outp)[grow * N + gcol] = (bf16_t)v;
                }
            }
        }
    }
}

// ---------------- fused causal attention ----------------
// qkv: [B*T, 3072] bf16 (q | k | v each 1024 cols, col = h*64+d)
// out: [B*T, 1024] bf16 (col = h*64+d)
// 1 block per (b,h); 4 waves; wave w owns Q rows [64w, 64w+64)
__global__ __launch_bounds__(256)
void attn_kernel(const bf16_t* __restrict__ qkv, bf16_t* __restrict__ outp)
{
    __shared__ __attribute__((aligned(16))) bf16_t Kt[64 * 72];
    __shared__ __attribute__((aligned(16))) bf16_t Vt[64 * 72];
    __shared__ __attribute__((aligned(16))) bf16_t Ps[4][16 * 72];

    const int tid = threadIdx.x, w = tid >> 6, lane = tid & 63;
    const int l16 = lane & 15, lg = lane >> 4;
    const int b = blockIdx.x >> 4, hh = blockIdx.x & 15;
    const bf16_t* pq = qkv + (long)(b * 256) * 3072 + hh * 64;

    bf16x8 qf[4][2];
#pragma unroll
    for (int fm = 0; fm < 4; ++fm)
#pragma unroll
        for (int kk = 0; kk < 2; ++kk)
            qf[fm][kk] = *(const bf16x8*)(pq + (long)(w * 64 + fm * 16 + l16) * 3072
                                          + kk * 32 + lg * 8);

    f32x4 o[4][4] = {};
    float mrun[4][4], lrun[4][4];
#pragma unroll
    for (int i = 0; i < 4; ++i)
#pragma unroll
        for (int j = 0; j < 4; ++j) { mrun[i][j] = -__builtin_inff(); lrun[i][j] = 0.f; }

    for (int st = 0; st < 4; ++st) {
        __syncthreads();
        // stage K tile [64 x 64] and V^T tile [64 x 64] for s in [64*st, 64*st+64)
#pragma unroll
        for (int i = 0; i < 2; ++i) {
            int idx = i * 256 + tid;            // 0..511
            int sr = idx >> 3, sc = (idx & 7) * 8;
            const bf16_t* src = pq + (long)(st * 64 + sr) * 3072;
            bf16x8 kv = *(const bf16x8*)(src + 1024 + sc);
            *(bf16x8*)&Kt[sr * 72 + sc] = kv;
            bf16x8 vv = *(const bf16x8*)(src + 2048 + sc);
#pragma unroll
            for (int e = 0; e < 8; ++e) Vt[(sc + e) * 72 + sr] = vv[e];
        }
        __syncthreads();
        if (st > w) continue;

        // S = Q K^T
        f32x4 s[4][4] = {};
#pragma unroll
        for (int ks = 0; ks < 2; ++ks) {
            bf16x8 kb[4];
#pragma unroll
            for (int fs = 0; fs < 4; ++fs)
                kb[fs] = *(const bf16x8*)&Kt[(fs * 16 + l16) * 72 + ks * 32 + lg * 8];
#pragma unroll
            for (int fm = 0; fm < 4; ++fm)
#pragma unroll
                for (int fs = 0; fs < 4; ++fs)
                    s[fm][fs] = __builtin_amdgcn_mfma_f32_16x16x32_bf16(
                        qf[fm][ks], kb[fs], s[fm][fs], 0, 0, 0);
        }

#pragma unroll
        for (int fm = 0; fm < 4; ++fm) {
            // scale + causal mask
#pragma unroll
            for (int fs = 0; fs < 4; ++fs)
#pragma unroll
                for (int e = 0; e < 4; ++e) {
                    float v = s[fm][fs][e] * 0.03125f;   // C^-0.5, C=1024
                    if (st == w && (fs * 16 + l16) > (fm * 16 + lg * 4 + e))
                        v = -__builtin_inff();
                    s[fm][fs][e] = v;
                }
            // online softmax per row (row owned by 16 lanes sharing lg)
#pragma unroll
            for (int e = 0; e < 4; ++e) {
                float pm = fmaxf(fmaxf(s[fm][0][e], s[fm][1][e]),
                                 fmaxf(s[fm][2][e], s[fm][3][e]));
#pragma unroll
                for (int off = 1; off < 16; off <<= 1) pm = fmaxf(pm, __shfl_xor(pm, off));
                float mnew  = fmaxf(mrun[fm][e], pm);
                float alpha = __expf(mrun[fm][e] - mnew);
                float rs = 0.f;
#pragma unroll
                for (int fs = 0; fs < 4; ++fs) {
                    float p = __expf(s[fm][fs][e] - mnew);
                    s[fm][fs][e] = p;
                    rs += p;
                }
#pragma unroll
                for (int off = 1; off < 16; off <<= 1) rs += __shfl_xor(rs, off);
                lrun[fm][e] = lrun[fm][e] * alpha + rs;
                mrun[fm][e] = mnew;
#pragma unroll
                for (int fd = 0; fd < 4; ++fd) o[fm][fd][e] *= alpha;
            }
            // P -> LDS (bf16), then PV MFMA
#pragma unroll
            for (int fs = 0; fs < 4; ++fs)
#pragma unroll
                for (int e = 0; e < 4; ++e)
                    Ps[w][(lg * 4 + e) * 72 + fs * 16 + l16] = (bf16_t)s[fm][fs][e];
            bf16x8 ap0 = *(const bf16x8*)&Ps[w][l16 * 72 + lg * 8];
            bf16x8 ap1 = *(const bf16x8*)&Ps[w][l16 * 72 + 32 + lg * 8];
#pragma unroll
            for (int fd = 0; fd < 4; ++fd) {
                bf16x8 vb0 = *(const bf16x8*)&Vt[(fd * 16 + l16) * 72 + lg * 8];
                bf16x8 vb1 = *(const bf16x8*)&Vt[(fd * 16 + l16) * 72 + 32 + lg * 8];
                o[fm][fd] = __builtin_amdgcn_mfma_f32_16x16x32_bf16(ap0, vb0, o[fm][fd], 0, 0, 0);
                o[fm][fd] = __builtin_amdgcn_mfma_f32_16x16x32_bf16(ap1, vb1, o[fm][fd], 0, 0, 0);
            }
        }
    }

#pragma unroll
    for (int fm = 0; fm < 4; ++fm)
#pragma unroll
        for (int e = 0; e < 4; ++e) {
            float inv = 1.f / lrun[fm][e];
            long row = (long)b * 256 + w * 64 + fm * 16 + lg * 4 + e;
#pragma unroll
            for (int fd = 0; fd < 4; ++fd)
                outp[row * 1024 + hh * 64 + fd * 16 + l16] =
                    (bf16_t)(o[fm][fd][e] * inv);
        }
}

// ---------------- launch ----------------
extern "C" void kernel_launch(void* const* d_in, const int* in_sizes, int n_in,
                              void* d_out, int out_size, void* d_ws, size_t ws_size,
                              hipStream_t stream)
{
    (void)in_sizes; (void)n_in; (void)out_size; (void)ws_size;
    const float* x      = (const float*)d_in[0];
    const float* wq     = (const float*)d_in[1];
    const float* wk     = (const float*)d_in[2];
    const float* wv     = (const float*)d_in[3];
    const float* w_proj = (const float*)d_in[4];
    const float* b_proj = (const float*)d_in[5];
    const float* w1     = (const float*)d_in[6];
    const float* b1     = (const float*)d_in[7];
    const float* w2     = (const float*)d_in[8];
    const float* b2     = (const float*)d_in[9];
    const float* g1  = (const float*)d_in[10]; const float* be1 = (const float*)d_in[11];
    const float* g2  = (const float*)d_in[12]; const float* be2 = (const float*)d_in[13];
    const float* g3  = (const float*)d_in[14]; const float* be3 = (const float*)d_in[15];

    char* ws = (char*)d_ws;
    // compact layout, total 192,937,984 bytes (~184 MiB):
    bf16_t* wqkv  = (bf16_t*)(ws + 0);           //  6,291,456
    bf16_t* wproj = (bf16_t*)(ws + 6291456);     //  2,097,152
    bf16_t* w1t   = (bf16_t*)(ws + 8388608);     //  8,388,608
    bf16_t* w2t   = (bf16_t*)(ws + 16777216);    //  8,388,608
    bf16_t* h     = (bf16_t*)(ws + 25165824);    // 33,554,432 (LN1 out; later attn out; later start of u)
    bf16_t* qkv   = (bf16_t*)(ws + 58720256);    // 100,663,296
    bf16_t* attn  = h;                           // reuses h after qkv GEMM
    bf16_t* u     = h;                           // 134,217,728 over dead h+qkv
    bf16_t* y     = (bf16_t*)(ws + 159383552);   // 33,554,432 (LN2 out; FFN2 writes in-place)
    float*  x2    = (float*)d_out;               // residual stream lives in d_out
    bf16_t* tbuf  = y;                           // FFN2 out, in-place over y

    const int M = 16384;

    pack_qkv_w<<<12288, 256, 0, stream>>>(wq, wk, wv, wqkv);
    transpose_w<<<4096, 256, 0, stream>>>(w_proj, wproj, 10, 10);
    transpose_w<<<16384, 256, 0, stream>>>(w1, w1t, 10, 12);
    transpose_w<<<16384, 256, 0, stream>>>(w2, w2t, 12, 10);

    // h = LN1(x)
    ln_fwd<<<M, 256, 0, stream>>>(x, g1, be1, h);
    // qkv = h @ Wqkv^T
    gemm_bt<0><<<dim3(128, 24), 256, 0, stream>>>(h, wqkv, qkv, nullptr, nullptr, M, 3072, 1024);
    // attention (writes over h region, disjoint from qkv)
    attn_kernel<<<1024, 256, 0, stream>>>(qkv, attn);
    // x2 = x + attn @ Wproj^T + b_proj   -> d_out (f32)
    gemm_bt<1><<<dim3(128, 8), 256, 0, stream>>>(attn, wproj, x2, b_proj, x, M, 1024, 1024);
    // y = LN2(x2)
    ln_fwd<<<M, 256, 0, stream>>>(x2, g2, be2, y);
    // u = relu(y @ W1^T + b1)   (overwrites dead attn+qkv region)
    gemm_bt<2><<<dim3(128, 32), 256, 0, stream>>>(y, w1t, u, b1, nullptr, M, 4096, 1024);
    // tbuf = y + (u @ W2^T + b2)  (bf16, in-place over y)
    gemm_bt<3><<<dim3(128, 8), 256, 0, stream>>>(u, w2t, tbuf, b2, y, M, 1024, 4096);
    // d_out = x2 + LN3(tbuf)   (in-place on d_out)
    ln3_kernel<<<M, 256, 0, stream>>>(tbuf, g3, be3, (float*)d_out, x2);
}

// Round 3
// 966.968 us; speedup vs baseline: 1.0197x; 1.0197x over previous
//
#include <hip/hip_runtime.h>

typedef __bf16 bf16_t;
typedef __bf16 bf16x8 __attribute__((ext_vector_type(8)));
typedef float f32x4 __attribute__((ext_vector_type(4)));

#define LN_EPS 1e-3f

__device__ __forceinline__ void gload_lds16(const void* g, void* l) {
    __builtin_amdgcn_global_load_lds(
        (__attribute__((address_space(1))) void*)(g),
        (__attribute__((address_space(3))) void*)(l), 16, 0, 0);
}

// ---------------- weight prep ----------------
// out[(sel*1024 + h*64 + d)*1024 + c] = w_sel[h][c][d]
__global__ void pack_qkv_w(const float* __restrict__ wq, const float* __restrict__ wk,
                           const float* __restrict__ wv, bf16_t* __restrict__ outp)
{
    int idx = blockIdx.x * 256 + threadIdx.x;       // 0 .. 3*1024*1024-1
    int c   = idx & 1023;
    int n   = idx >> 10;
    int sel = n >> 10;
    int hd  = n & 1023;
    const float* src = (sel == 0) ? wq : (sel == 1) ? wk : wv;
    outp[idx] = (bf16_t)src[((hd >> 6) * 1024 + c) * 64 + (hd & 63)];
}

// out[n*K + k] = in[k*N + n]   (K = 1<<lgK, N = 1<<lgN)
__global__ void transpose_w(const float* __restrict__ in, bf16_t* __restrict__ outp,
                            int lgK, int lgN)
{
    long idx = (long)blockIdx.x * 256 + threadIdx.x;
    long k = idx & ((1L << lgK) - 1);
    long n = idx >> lgK;
    outp[idx] = (bf16_t)in[n + (k << lgN)];
}

// ---------------- layernorm (f32 in -> bf16 LN out) ----------------
__global__ __launch_bounds__(256)
void ln_fwd(const float* __restrict__ in, const float* __restrict__ g,
            const float* __restrict__ be, bf16_t* __restrict__ outp)
{
    const long row = blockIdx.x;
    const int t = threadIdx.x;
    float4 v = ((const float4*)(in + row * 1024))[t];
    float s  = v.x + v.y + v.z + v.w;
    float sq = v.x * v.x + v.y * v.y + v.z * v.z + v.w * v.w;
#pragma unroll
    for (int off = 1; off < 64; off <<= 1) {
        s  += __shfl_xor(s, off);
        sq += __shfl_xor(sq, off);
    }
    __shared__ float red[8];
    if ((t & 63) == 0) { red[(t >> 6) * 2] = s; red[(t >> 6) * 2 + 1] = sq; }
    __syncthreads();
    s  = red[0] + red[2] + red[4] + red[6];
    sq = red[1] + red[3] + red[5] + red[7];
    float mean = s * 0.0009765625f;
    float var  = sq * 0.0009765625f - mean * mean;
    float rstd = rsqrtf(var + LN_EPS);
    float4 gv = ((const float4*)g)[t];
    float4 bv = ((const float4*)be)[t];
    union { bf16_t h[4]; uint2 u; } pk;
    pk.h[0] = (bf16_t)((v.x - mean) * rstd * gv.x + bv.x);
    pk.h[1] = (bf16_t)((v.y - mean) * rstd * gv.y + bv.y);
    pk.h[2] = (bf16_t)((v.z - mean) * rstd * gv.z + bv.z);
    pk.h[3] = (bf16_t)((v.w - mean) * rstd * gv.w + bv.w);
    *(uint2*)(outp + row * 1024 + t * 4) = pk.u;
}

// ---------------- final layernorm (bf16 in + f32 res -> f32 out, res may == out) ----------------
__global__ __launch_bounds__(256)
void ln3_kernel(const bf16_t* __restrict__ in, const float* __restrict__ g,
                const float* __restrict__ be, float* outp, const float* res)
{
    const long row = blockIdx.x;
    const int t = threadIdx.x;
    union { uint2 u; bf16_t h[4]; } pk;
    pk.u = *(const uint2*)(in + row * 1024 + t * 4);
    float v0 = (float)pk.h[0], v1 = (float)pk.h[1], v2 = (float)pk.h[2], v3 = (float)pk.h[3];
    float s  = v0 + v1 + v2 + v3;
    float sq = v0 * v0 + v1 * v1 + v2 * v2 + v3 * v3;
#pragma unroll
    for (int off = 1; off < 64; off <<= 1) {
        s  += __shfl_xor(s, off);
        sq += __shfl_xor(sq, off);
    }
    __shared__ float red[8];
    if ((t & 63) == 0) { red[(t >> 6) * 2] = s; red[(t >> 6) * 2 + 1] = sq; }
    __syncthreads();
    s  = red[0] + red[2] + red[4] + red[6];
    sq = red[1] + red[3] + red[5] + red[7];
    float mean = s * 0.0009765625f;
    float var  = sq * 0.0009765625f - mean * mean;
    float rstd = rsqrtf(var + LN_EPS);
    float4 gv = ((const float4*)g)[t];
    float4 bv = ((const float4*)be)[t];
    float4 rv = ((const float4*)(res + row * 1024))[t];
    float4 ov;
    ov.x = rv.x + (v0 - mean) * rstd * gv.x + bv.x;
    ov.y = rv.y + (v1 - mean) * rstd * gv.y + bv.y;
    ov.z = rv.z + (v2 - mean) * rstd * gv.z + bv.z;
    ov.w = rv.w + (v3 - mean) * rstd * gv.w + bv.w;
    ((float4*)outp)[row * 256 + t] = ov;
}

// ---------------- GEMM: C[M,N] = A[M,K] * Bt[N,K]^T ----------------
// MODE 0: out bf16 = acc
// MODE 1: out f32  = acc + bias[col] + addf32[row,col]
// MODE 2: out bf16 = relu(acc + bias[col])
// MODE 3: out bf16 = acc + bias[col] + (float)addbf16[row,col]   (outp may == addp, elementwise)
template<int MODE>
__global__ __launch_bounds__(256)
void gemm_bt(const bf16_t* __restrict__ A, const bf16_t* __restrict__ Bt,
             void* outp, const float* __restrict__ bias,
             const void* addp, int M, int N, int K)
{
    __shared__ __attribute__((aligned(16))) bf16_t As[128 * 64];
    __shared__ __attribute__((aligned(16))) bf16_t Bs[128 * 64];
    const int tid  = threadIdx.x;
    const int w    = tid >> 6, lane = tid & 63;
    const int l16  = lane & 15, lg = lane >> 4;
    const int wm   = w >> 1, wn = w & 1;
    const long m0  = (long)blockIdx.x * 128;
    const long n0  = (long)blockIdx.y * 128;
    const int srow = lane >> 3;            // 0..7
    const int scol = (lane & 7) * 8;       // element offset in a 64-wide row

    f32x4 acc[4][4] = {};
    const int nkt = K >> 6;
    const bf16_t* Abase = A  + (m0 + 32 * w + srow) * (long)K + scol;
    const bf16_t* Bbase = Bt + (n0 + 32 * w + srow) * (long)K + scol;

    for (int kt = 0; kt < nkt; ++kt) {
        __syncthreads();
#pragma unroll
        for (int i = 0; i < 4; ++i) {
            gload_lds16(Abase + (long)8 * i * K + kt * 64, &As[(32 * w + 8 * i) * 64]);
            gload_lds16(Bbase + (long)8 * i * K + kt * 64, &Bs[(32 * w + 8 * i) * 64]);
        }
        asm volatile("s_waitcnt vmcnt(0)" ::: "memory");
        __syncthreads();
#pragma unroll
        for (int kk = 0; kk < 2; ++kk) {
            bf16x8 a[4], b[4];
#pragma unroll
            for (int f = 0; f < 4; ++f) {
                a[f] = *(const bf16x8*)&As[(wm * 64 + f * 16 + l16) * 64 + kk * 32 + lg * 8];
                b[f] = *(const bf16x8*)&Bs[(wn * 64 + f * 16 + l16) * 64 + kk * 32 + lg * 8];
            }
#pragma unroll
            for (int fm = 0; fm < 4; ++fm)
#pragma unroll
                for (int fn = 0; fn < 4; ++fn)
                    acc[fm][fn] = __builtin_amdgcn_mfma_f32_16x16x32_bf16(
                        a[fm], b[fn], acc[fm][fn], 0, 0, 0);
        }
    }

#pragma unroll
    for (int fm = 0; fm < 4; ++fm) {
#pragma unroll
        for (int fn = 0; fn < 4; ++fn) {
            const long gcol = n0 + wn * 64 + fn * 16 + l16;
            float bv = 0.f;
            if (MODE != 0) bv = bias[gcol];
#pragma unroll
            for (int e = 0; e < 4; ++e) {
                const long grow = m0 + wm * 64 + fm * 16 + lg * 4 + e;
                float v = acc[fm][fn][e];
                if (MODE == 0) {
                    ((bf16_t*)outp)[grow * N + gcol] = (bf16_t)v;
                } else if (MODE == 1) {
                    v += bv + ((const float*)addp)[grow * N + gcol];
                    ((float*)outp)[grow * N + gcol] = v;
                } else if (MODE == 2) {
                    v += bv; v = v > 0.f ? v : 0.f;
                    ((bf16_t*)outp)[grow * N + gcol] = (bf16_t)v;
                } else {
                    v += bv + (float)((const bf16_t*)addp)[grow * N + gcol];
                    ((bf16_t*)outp)[grow * N + gcol] = (bf16_t)v;
                }
            }
        }
    }
}

// ---------------- fused causal attention ----------------
// qkv: [B*T, 3072] bf16 (q | k | v each 1024 cols, col = h*64+d)
// out: [B*T, 1024] bf16 (col = h*64+d)
// 1 block per (b,h); 4 waves; wave w owns Q rows [64w, 64w+64)
__global__ __launch_bounds__(256)
void attn_kernel(const bf16_t* __restrict__ qkv, bf16_t* __restrict__ outp)
{
    __shared__ __attribute__((aligned(16))) bf16_t Kt[64 * 72];
    __shared__ __attribute__((aligned(16))) bf16_t Vt[64 * 72];
    __shared__ __attribute__((aligned(16))) bf16_t Ps[4][16 * 72];

    const int tid = threadIdx.x, w = tid >> 6, lane = tid & 63;
    const int l16 = lane & 15, lg = lane >> 4;
    const int b = blockIdx.x >> 4, hh = blockIdx.x & 15;
    const bf16_t* pq = qkv + (long)(b * 256) * 3072 + hh * 64;

    bf16x8 qf[4][2];
#pragma unroll
    for (int fm = 0; fm < 4; ++fm)
#pragma unroll
        for (int kk = 0; kk < 2; ++kk)
            qf[fm][kk] = *(const bf16x8*)(pq + (long)(w * 64 + fm * 16 + l16) * 3072
                                          + kk * 32 + lg * 8);

    f32x4 o[4][4] = {};
    float mrun[4][4], lrun[4][4];
#pragma unroll
    for (int i = 0; i < 4; ++i)
#pragma unroll
        for (int j = 0; j < 4; ++j) { mrun[i][j] = -__builtin_inff(); lrun[i][j] = 0.f; }

    for (int st = 0; st < 4; ++st) {
        __syncthreads();
        // stage K tile [64 x 64] and V^T tile [64 x 64] for s in [64*st, 64*st+64)
#pragma unroll
        for (int i = 0; i < 2; ++i) {
            int idx = i * 256 + tid;            // 0..511
            int sr = idx >> 3, sc = (idx & 7) * 8;
            const bf16_t* src = pq + (long)(st * 64 + sr) * 3072;
            bf16x8 kv = *(const bf16x8*)(src + 1024 + sc);
            *(bf16x8*)&Kt[sr * 72 + sc] = kv;
            bf16x8 vv = *(const bf16x8*)(src + 2048 + sc);
#pragma unroll
            for (int e = 0; e < 8; ++e) Vt[(sc + e) * 72 + sr] = vv[e];
        }
        __syncthreads();
        if (st > w) continue;

        // S = Q K^T
        f32x4 s[4][4] = {};
#pragma unroll
        for (int ks = 0; ks < 2; ++ks) {
            bf16x8 kb[4];
#pragma unroll
            for (int fs = 0; fs < 4; ++fs)
                kb[fs] = *(const bf16x8*)&Kt[(fs * 16 + l16) * 72 + ks * 32 + lg * 8];
#pragma unroll
            for (int fm = 0; fm < 4; ++fm)
#pragma unroll
                for (int fs = 0; fs < 4; ++fs)
                    s[fm][fs] = __builtin_amdgcn_mfma_f32_16x16x32_bf16(
                        qf[fm][ks], kb[fs], s[fm][fs], 0, 0, 0);
        }

#pragma unroll
        for (int fm = 0; fm < 4; ++fm) {
            // scale + causal mask
#pragma unroll
            for (int fs = 0; fs < 4; ++fs)
#pragma unroll
                for (int e = 0; e < 4; ++e) {
                    float v = s[fm][fs][e] * 0.03125f;   // C^-0.5, C=1024
                    if (st == w && (fs * 16 + l16) > (fm * 16 + lg * 4 + e))
                        v = -__builtin_inff();
                    s[fm][fs][e] = v;
                }
            // online softmax per row (row owned by 16 lanes sharing lg)
#pragma unroll
            for (int e = 0; e < 4; ++e) {
                float pm = fmaxf(fmaxf(s[fm][0][e], s[fm][1][e]),
                                 fmaxf(s[fm][2][e], s[fm][3][e]));
#pragma unroll
                for (int off = 1; off < 16; off <<= 1) pm = fmaxf(pm, __shfl_xor(pm, off));
                float mnew  = fmaxf(mrun[fm][e], pm);
                float alpha = __expf(mrun[fm][e] - mnew);
                float rs = 0.f;
#pragma unroll
                for (int fs = 0; fs < 4; ++fs) {
                    float p = __expf(s[fm][fs][e] - mnew);
                    s[fm][fs][e] = p;
                    rs += p;
                }
#pragma unroll
                for (int off = 1; off < 16; off <<= 1) rs += __shfl_xor(rs, off);
                lrun[fm][e] = lrun[fm][e] * alpha + rs;
                mrun[fm][e] = mnew;
#pragma unroll
                for (int fd = 0; fd < 4; ++fd) o[fm][fd][e] *= alpha;
            }
            // P -> LDS (bf16), then PV MFMA
#pragma unroll
            for (int fs = 0; fs < 4; ++fs)
#pragma unroll
                for (int e = 0; e < 4; ++e)
                    Ps[w][(lg * 4 + e) * 72 + fs * 16 + l16] = (bf16_t)s[fm][fs][e];
            bf16x8 ap0 = *(const bf16x8*)&Ps[w][l16 * 72 + lg * 8];
            bf16x8 ap1 = *(const bf16x8*)&Ps[w][l16 * 72 + 32 + lg * 8];
#pragma unroll
            for (int fd = 0; fd < 4; ++fd) {
                bf16x8 vb0 = *(const bf16x8*)&Vt[(fd * 16 + l16) * 72 + lg * 8];
                bf16x8 vb1 = *(const bf16x8*)&Vt[(fd * 16 + l16) * 72 + 32 + lg * 8];
                o[fm][fd] = __builtin_amdgcn_mfma_f32_16x16x32_bf16(ap0, vb0, o[fm][fd], 0, 0, 0);
                o[fm][fd] = __builtin_amdgcn_mfma_f32_16x16x32_bf16(ap1, vb1, o[fm][fd], 0, 0, 0);
            }
        }
    }

#pragma unroll
    for (int fm = 0; fm < 4; ++fm)
#pragma unroll
        for (int e = 0; e < 4; ++e) {
            float inv = 1.f / lrun[fm][e];
            long row = (long)b * 256 + w * 64 + fm * 16 + lg * 4 + e;
#pragma unroll
            for (int fd = 0; fd < 4; ++fd)
                outp[row * 1024 + hh * 64 + fd * 16 + l16] =
                    (bf16_t)(o[fm][fd][e] * inv);
        }
}

// ---------------- launch ----------------
extern "C" void kernel_launch(void* const* d_in, const int* in_sizes, int n_in,
                              void* d_out, int out_size, void* d_ws, size_t ws_size,
                              hipStream_t stream)
{
    (void)in_sizes; (void)n_in; (void)out_size; (void)ws_size;
    const float* x      = (const float*)d_in[0];
    const float* wq     = (const float*)d_in[1];
    const float* wk     = (const float*)d_in[2];
    const float* wv     = (const float*)d_in[3];
    const float* w_proj = (const float*)d_in[4];
    const float* b_proj = (const float*)d_in[5];
    const float* w1     = (const float*)d_in[6];
    const float* b1     = (const float*)d_in[7];
    const float* w2     = (const float*)d_in[8];
    const float* b2     = (const float*)d_in[9];
    const float* g1  = (const float*)d_in[10]; const float* be1 = (const float*)d_in[11];
    const float* g2  = (const float*)d_in[12]; const float* be2 = (const float*)d_in[13];
    const float* g3  = (const float*)d_in[14]; const float* be3 = (const float*)d_in[15];

    char* ws = (char*)d_ws;
    // compact layout, total 192,937,984 bytes (~184 MiB):
    bf16_t* wqkv  = (bf16_t*)(ws + 0);           //  6,291,456
    bf16_t* wproj = (bf16_t*)(ws + 6291456);     //  2,097,152
    bf16_t* w1t   = (bf16_t*)(ws + 8388608);     //  8,388,608
    bf16_t* w2t   = (bf16_t*)(ws + 16777216);    //  8,388,608
    bf16_t* h     = (bf16_t*)(ws + 25165824);    // 33,554,432 (LN1 out; later attn out; later start of u)
    bf16_t* qkv   = (bf16_t*)(ws + 58720256);    // 100,663,296
    bf16_t* attn  = h;                           // reuses h after qkv GEMM
    bf16_t* u     = h;                           // 134,217,728 over dead h+qkv
    bf16_t* y     = (bf16_t*)(ws + 159383552);   // 33,554,432 (LN2 out; FFN2 writes in-place)
    float*  x2    = (float*)d_out;               // residual stream lives in d_out
    bf16_t* tbuf  = y;                           // FFN2 out, in-place over y

    const int M = 16384;

    pack_qkv_w<<<12288, 256, 0, stream>>>(wq, wk, wv, wqkv);
    transpose_w<<<4096, 256, 0, stream>>>(w_proj, wproj, 10, 10);
    transpose_w<<<16384, 256, 0, stream>>>(w1, w1t, 10, 12);
    transpose_w<<<16384, 256, 0, stream>>>(w2, w2t, 12, 10);

    // h = LN1(x)
    ln_fwd<<<M, 256, 0, stream>>>(x, g1, be1, h);
    // qkv = h @ Wqkv^T
    gemm_bt<0><<<dim3(128, 24), 256, 0, stream>>>(h, wqkv, qkv, nullptr, nullptr, M, 3072, 1024);
    // attention (writes over h region, disjoint from qkv)
    attn_kernel<<<1024, 256, 0, stream>>>(qkv, attn);
    // x2 = x + attn @ Wproj^T + b_proj   -> d_out (f32)
    gemm_bt<1><<<dim3(128, 8), 256, 0, stream>>>(attn, wproj, x2, b_proj, x, M, 1024, 1024);
    // y = LN2(x2)
    ln_fwd<<<M, 256, 0, stream>>>(x2, g2, be2, y);
    // u = relu(y @ W1^T + b1)   (overwrites dead attn+qkv region)
    gemm_bt<2><<<dim3(128, 32), 256, 0, stream>>>(y, w1t, u, b1, nullptr, M, 4096, 1024);
    // tbuf = y + (u @ W2^T + b2)  (bf16, in-place over y)
    gemm_bt<3><<<dim3(128, 8), 256, 0, stream>>>(u, w2t, tbuf, b2, y, M, 1024, 4096);
    // d_out = x2 + LN3(tbuf)   (in-place on d_out)
    ln3_kernel<<<M, 256, 0, stream>>>(tbuf, g3, be3, (float*)d_out, x2);
}